// Round 14
// baseline (360.678 us; speedup 1.0000x reference)
//
#include <hip/hip_runtime.h>
#include <stdint.h>

// ---------------------------------------------------------------------------
// GCN forward on MI355X:
//   d = rsqrt(A.sum(1));  out = dA d relu(dA d (X W1) + b1) W2 + b2 (fused)
// Big A_bf GEMMs: 256x256 tile, BK=32, 8 waves, split-K=4. B operand is
// loaded GLOBAL->VGPR (L2-resident slab, reg double-buffer, static names);
// LDS carries A only (2 x 16KB, stage-1-ahead, XOR swizzle). One vmcnt(0)
// + barrier per K-tile (drains full-tile-aged loads: ~free). setprio on
// MFMA cluster. XCD-aware placement.
// ---------------------------------------------------------------------------

typedef __attribute__((ext_vector_type(8))) __bf16 bf16x8;
typedef __attribute__((ext_vector_type(4))) float f32x4;
typedef __attribute__((ext_vector_type(8))) unsigned short u16x8;

__device__ __forceinline__ unsigned short f2bf(float f) {
  union { float f; uint32_t u; } v; v.f = f;
  uint32_t u = v.u;
  return (unsigned short)((u + 0x7fffu + ((u >> 16) & 1u)) >> 16);  // RNE
}

__device__ __forceinline__ float bf2f(unsigned short u) {
  union { uint32_t u; float f; } v; v.u = ((uint32_t)u) << 16; return v.f;
}

__device__ __forceinline__ void async_cp16(const void* g, void* lds) {
  auto gp = (const __attribute__((address_space(1))) uint32_t*)g;
  auto lp = (__attribute__((address_space(3))) uint32_t*)lds;
  __builtin_amdgcn_global_load_lds(gp, lp, 16, 0, 0);
}

// --- kernel 1: per-row sum of fp32 A + fp32->bf16 conversion ----------------
__global__ __launch_bounds__(256) void k_rowsum_convert(
    const float* __restrict__ A, unsigned short* __restrict__ Abf,
    float* __restrict__ dvec, int ncols) {
  const int row = blockIdx.x;
  const float* arow = A + (size_t)row * ncols;
  unsigned short* orow = Abf + (size_t)row * ncols;
  float s = 0.f;
  for (int c = threadIdx.x * 4; c < ncols; c += 256 * 4) {
    float4 v = *(const float4*)(arow + c);
    s += (v.x + v.y) + (v.z + v.w);
    ushort4 o;
    o.x = f2bf(v.x); o.y = f2bf(v.y); o.z = f2bf(v.z); o.w = f2bf(v.w);
    *(ushort4*)(orow + c) = o;
  }
  #pragma unroll
  for (int off = 32; off > 0; off >>= 1) s += __shfl_down(s, off);
  __shared__ float red[4];
  if ((threadIdx.x & 63) == 0) red[threadIdx.x >> 6] = s;
  __syncthreads();
  if (threadIdx.x == 0) {
    float t = (red[0] + red[1]) + (red[2] + red[3]);
    dvec[row] = 1.0f / sqrtf(t);
  }
}

// --- kernel 2: elementwise fp32 -> bf16 -------------------------------------
__global__ __launch_bounds__(256) void k_f32_to_bf16(
    const float* __restrict__ in, unsigned short* __restrict__ out, int n4) {
  int i = blockIdx.x * 256 + threadIdx.x;
  if (i < n4) {
    float4 v = ((const float4*)in)[i];
    ushort4 o;
    o.x = f2bf(v.x); o.y = f2bf(v.y); o.z = f2bf(v.z); o.w = f2bf(v.w);
    ((ushort4*)out)[i] = o;
  }
}

// --- kernel 3: transpose + convert 512x512 weight: out[n][k] = in[k][n] -----
__global__ __launch_bounds__(256) void k_transpose_bf16(
    const float* __restrict__ in, unsigned short* __restrict__ out, int dim) {
  int o = blockIdx.x * 256 + threadIdx.x;
  if (o < dim * dim) {
    int k = o % dim;
    int n = o / dim;
    out[o] = f2bf(in[k * dim + n]);
  }
}

// --- small GEMM (proven): C[M,N] = bf16(dvec[col] * Aop[M,K] * Bt[N,K]^T) ---
template <int MODE>
__global__ __launch_bounds__(256, 2) void gemm_bt(
    const unsigned short* __restrict__ Aop,
    const unsigned short* __restrict__ Bt,
    void* __restrict__ Cout,
    const float* __restrict__ dvec,
    const float* __restrict__ bias,
    int M, int N, int K) {
  constexpr int BM = 128, BN = 64, BK = 32;
  __shared__ unsigned short As[BM * BK];
  __shared__ unsigned short Bs[BN * BK];

  const int tid = threadIdx.x;
  const int w = tid >> 6;
  const int l = tid & 63;
  const int rowBase = blockIdx.y * BM;
  const int colBase = blockIdx.x * BN;
  const int waveM = w >> 1;
  const int waveN = w & 1;

  f32x4 acc[4][2];
  const f32x4 fz = {0.f, 0.f, 0.f, 0.f};
  #pragma unroll
  for (int m = 0; m < 4; ++m)
    #pragma unroll
    for (int n = 0; n < 2; ++n) acc[m][n] = fz;

  const int chunkRow = l >> 2;
  const int kOff = (l & 3) * 8;
  const unsigned short* gA0 = Aop + (size_t)(rowBase + w * 16 + chunkRow) * K + kOff;
  const unsigned short* gA1 = gA0 + (size_t)64 * K;
  const unsigned short* gB0 = Bt + (size_t)(colBase + w * 16 + chunkRow) * K + kOff;
  unsigned short* lA0 = As + w * 512;
  unsigned short* lA1 = As + (w + 4) * 512;
  unsigned short* lB0 = Bs + w * 512;

  const int kfrag = (l >> 4) * 8;
  const int lrow = l & 15;

  for (int k0 = 0; k0 < K; k0 += BK) {
    async_cp16(gA0 + k0, lA0);
    async_cp16(gA1 + k0, lA1);
    async_cp16(gB0 + k0, lB0);
    __syncthreads();

    bf16x8 af[4], bfr[2];
    #pragma unroll
    for (int m = 0; m < 4; ++m)
      af[m] = *(const bf16x8*)(As + (waveM * 64 + m * 16 + lrow) * BK + kfrag);
    #pragma unroll
    for (int n = 0; n < 2; ++n)
      bfr[n] = *(const bf16x8*)(Bs + (waveN * 32 + n * 16 + lrow) * BK + kfrag);

    #pragma unroll
    for (int m = 0; m < 4; ++m)
      #pragma unroll
      for (int n = 0; n < 2; ++n)
        acc[m][n] = __builtin_amdgcn_mfma_f32_16x16x32_bf16(af[m], bfr[n],
                                                            acc[m][n], 0, 0, 0);
    __syncthreads();
  }

  const int erow0 = rowBase + waveM * 64 + (l >> 4) * 4;
  const int ecol0 = colBase + waveN * 32 + (l & 15);
  #pragma unroll
  for (int m = 0; m < 4; ++m) {
    #pragma unroll
    for (int n = 0; n < 2; ++n) {
      #pragma unroll
      for (int j = 0; j < 4; ++j) {
        const int rowg = erow0 + m * 16 + j;
        const int colg = ecol0 + n * 16;
        float v = acc[m][n][j];
        if (MODE == 0) {
          v *= dvec[colg];
          ((unsigned short*)Cout)[(size_t)rowg * N + colg] = f2bf(v);
        }
      }
    }
  }
}

// --- big GEMM: Pout[z][M][N] = Aop[M,Kslab] * Bt[N,Kslab]^T (bf16 partial) --
// 256x256, BK=32, 8 waves (2Mx4N, wave out 128x64). A: LDS 2x16KB,
// stage-1-ahead via global_load_lds, XOR-swizzled. B: global->VGPR direct
// (L2-resident slab), reg double-buffer with static names, loaded 1 tile
// ahead. Per tile: [vmcnt(0); barrier] certifies A(t) DMA + B(t) regs
// (all issued in body t-1), then free-run body. Linear grid 256 blocks;
// requires M=8192, N=512, KSPLIT=4.
// XCD decode: id = q + 8*s -> z=q>>1, y=(q&1)*16+(s>>1), x=s&1.
__global__ __launch_bounds__(512, 2) void gemm_bigRB(
    const unsigned short* __restrict__ Aop,
    const unsigned short* __restrict__ Bt,
    unsigned short* __restrict__ Pout,
    int M, int N, int K, int kLen) {
  constexpr int BK = 32;
  __shared__ char lds[2 * 16384];  // 2 x A 16KB

  const int tid = threadIdx.x;
  const int w = tid >> 6;       // 0..7
  const int l = tid & 63;

  const int id = blockIdx.x;
  const int q = id & 7, s = id >> 3;
  const int bx = s & 1;
  const int by = ((q & 1) << 4) | (s >> 1);
  const int bz = q >> 1;

  const int rowBase = by * 256;
  const int colBase = bx * 256;
  const int kBase = bz * kLen;
  const int waveM = w >> 2;     // 0..1 -> 128-row slab
  const int waveN = w & 3;      // 0..3 -> 64-col slab

  f32x4 acc[8][4];
  const f32x4 fz = {0.f, 0.f, 0.f, 0.f};
  #pragma unroll
  for (int m = 0; m < 8; ++m)
    #pragma unroll
    for (int n = 0; n < 4; ++n) acc[m][n] = fz;

  // ---- A staging: wave w owns rows [w*32, w*32+32): 2 cp16 of 16 rows.
  // lane l -> row R0+(l>>2), 16B slot l&3; pre-swizzled source slot =
  // (l&3) ^ ((l>>3)&3)  [= slot ^ ((row>>1)&3)]; linear LDS dest.
  const int srcElem = ((l & 3) ^ ((l >> 3) & 3)) * 8;
  const unsigned short* aSrc =
      Aop + (size_t)(rowBase + w * 32 + (l >> 2)) * K + kBase + srcElem;
  const int dstTh = w * 2048 + l * 16;

#define STAGE_A(tt, bb)                                                   \
  {                                                                       \
    const size_t o = (size_t)(tt) * BK;                                   \
    async_cp16(aSrc + o, lds + (bb) + dstTh);                             \
    async_cp16(aSrc + (size_t)16 * K + o, lds + (bb) + dstTh + 1024);     \
  }

  const int lrow = l & 15;
  const int kq = l >> 4;               // 16B k-slot
  const int xr = (lrow >> 1) & 3;      // (row>>1)&3 for this lane's rows
  const int slotByte = ((kq ^ xr) << 4);
  const int aRow0 = (waveM * 128 + lrow) * 64;

  // B lane base: row = colBase + waveN*64 + n*16 + lrow, col = kBase + ...
  const unsigned short* bLane =
      Bt + (size_t)(colBase + waveN * 64 + lrow) * K + kBase + kq * 8;

  const int nt = kLen / BK;  // 64

  // prologue: stage A(0) -> buf0; load B(0) -> bA regs
  STAGE_A(0, 0);
  bf16x8 bA[4], bB[4];
  #pragma unroll
  for (int n = 0; n < 4; ++n)
    bA[n] = *(const bf16x8*)(bLane + (size_t)n * 16 * K);

  // body macro: certify tile t (vmcnt(0)+barrier), read A-frags, issue
  // next-tile A-stage + B-loads, 32 MFMAs with CUR B regs.
#define BODY(t, bufoff, CUR, NXT)                                         \
  {                                                                       \
    asm volatile("s_waitcnt vmcnt(0)" ::: "memory");                      \
    __builtin_amdgcn_s_barrier();                                         \
    bf16x8 af[8];                                                         \
    _Pragma("unroll")                                                     \
    for (int i = 0; i < 8; ++i)                                           \
      af[i] = *(const bf16x8*)(lds + (bufoff) + aRow0 + i * 16 * 64 +     \
                               slotByte);                                 \
    if ((t) + 1 < nt) {                                                   \
      STAGE_A((t) + 1, (bufoff) ^ 16384);                                 \
      _Pragma("unroll")                                                   \
      for (int n = 0; n < 4; ++n)                                         \
        NXT[n] = *(const bf16x8*)(bLane + (size_t)n * 16 * K +            \
                                  (size_t)((t) + 1) * BK);                \
    }                                                                     \
    __builtin_amdgcn_s_setprio(1);                                        \
    _Pragma("unroll")                                                     \
    for (int i = 0; i < 8; ++i)                                           \
      _Pragma("unroll")                                                   \
      for (int n = 0; n < 4; ++n)                                         \
        acc[i][n] = __builtin_amdgcn_mfma_f32_16x16x32_bf16(              \
            af[i], CUR[n], acc[i][n], 0, 0, 0);                           \
    __builtin_amdgcn_s_setprio(0);                                        \
  }

  for (int t2 = 0; t2 < nt; t2 += 2) {
    BODY(t2, 0, bA, bB);
    BODY(t2 + 1, 16384, bB, bA);
  }
#undef BODY
#undef STAGE_A

  // epilogue: bf16 partial write. C/D layout: col = lane&15, row = (l>>4)*4+j
  unsigned short* pz = Pout + (size_t)bz * M * N;
  const int erow0 = rowBase + waveM * 128 + (l >> 4) * 4;
  const int ecol0 = colBase + waveN * 64 + (l & 15);
  #pragma unroll
  for (int m = 0; m < 8; ++m) {
    #pragma unroll
    for (int n = 0; n < 4; ++n) {
      #pragma unroll
      for (int j = 0; j < 4; ++j) {
        pz[(size_t)(erow0 + m * 16 + j) * N + ecol0 + n * 16] =
            f2bf(acc[m][n][j]);
      }
    }
  }
}

// --- reduce over 4 bf16 partials + epilogue ---------------------------------
// MODE 1: out bf16 = relu(d_row * sum + bias[col])
// MODE 2: out fp32 = d_row * sum + bias[col]
template <int MODE>
__global__ __launch_bounds__(256) void k_reduce(
    const unsigned short* __restrict__ parts,
    const float* __restrict__ dvec,
    const float* __restrict__ bias,
    void* __restrict__ outp, int M, int N) {
  const size_t MN = (size_t)M * N;
  const size_t idx = ((size_t)blockIdx.x * 256 + threadIdx.x) * 8;
  if (idx >= MN) return;
  const int row = (int)(idx / N);
  const int col = (int)(idx % N);
  const float di = dvec[row];
  float s[8] = {0, 0, 0, 0, 0, 0, 0, 0};
  #pragma unroll
  for (int z = 0; z < 4; ++z) {
    u16x8 v = *(const u16x8*)(parts + z * MN + idx);
    #pragma unroll
    for (int e = 0; e < 8; ++e) s[e] += bf2f(v[e]);
  }
  if (MODE == 1) {
    ushort4 o0, o1;
    unsigned short tmp[8];
    #pragma unroll
    for (int e = 0; e < 8; ++e) {
      float v = di * s[e] + bias[col + e];
      v = v > 0.f ? v : 0.f;
      tmp[e] = f2bf(v);
    }
    o0.x = tmp[0]; o0.y = tmp[1]; o0.z = tmp[2]; o0.w = tmp[3];
    o1.x = tmp[4]; o1.y = tmp[5]; o1.z = tmp[6]; o1.w = tmp[7];
    *(ushort4*)((unsigned short*)outp + idx) = o0;
    *(ushort4*)((unsigned short*)outp + idx + 4) = o1;
  } else {
    float4 o0, o1;
    o0.x = di * s[0] + bias[col + 0];
    o0.y = di * s[1] + bias[col + 1];
    o0.z = di * s[2] + bias[col + 2];
    o0.w = di * s[3] + bias[col + 3];
    o1.x = di * s[4] + bias[col + 4];
    o1.y = di * s[5] + bias[col + 5];
    o1.z = di * s[6] + bias[col + 6];
    o1.w = di * s[7] + bias[col + 7];
    *(float4*)((float*)outp + idx) = o0;
    *(float4*)((float*)outp + idx + 4) = o1;
  }
}

extern "C" void kernel_launch(void* const* d_in, const int* in_sizes, int n_in,
                              void* d_out, int out_size, void* d_ws, size_t ws_size,
                              hipStream_t stream) {
  const float* X  = (const float*)d_in[0];   // [8192, 512]
  const float* A  = (const float*)d_in[1];   // [8192, 8192]
  const float* W1 = (const float*)d_in[2];   // [512, 512]
  const float* b1 = (const float*)d_in[3];   // [512]
  const float* W2 = (const float*)d_in[4];   // [512, 512]
  const float* b2 = (const float*)d_in[5];   // [512]
  float* out = (float*)d_out;                // [8192, 512] fp32

  constexpr int NN = 8192, IN = 512, HID = 512;
  constexpr int KSPLIT = 4;

  // workspace (~177 MiB): d | A_bf | W1t | W2t | P0 | P1 | parts
  char* ws = (char*)d_ws;
  float* ddeg = (float*)ws;                                        // 32KB
  unsigned short* Abf = (unsigned short*)(ws + (32 << 10));        // 128MiB
  unsigned short* W1t = Abf + (size_t)NN * NN;                     // 512KiB
  unsigned short* W2t = W1t + IN * HID;                            // 512KiB
  unsigned short* P0  = W2t + HID * HID;                           // 8MiB
  unsigned short* P1  = P0 + (size_t)NN * HID;                     // 8MiB
  unsigned short* parts = P1 + (size_t)NN * HID;                   // 32MiB

  // 1) degrees + A -> bf16
  k_rowsum_convert<<<NN, 256, 0, stream>>>(A, Abf, ddeg, NN);
  // 2) X -> bf16 (into P0)
  k_f32_to_bf16<<<(NN * IN / 4 + 255) / 256, 256, 0, stream>>>(X, P0, NN * IN / 4);
  // 3) weights transposed+bf16
  k_transpose_bf16<<<(IN * HID + 255) / 256, 256, 0, stream>>>(W1, W1t, IN);
  k_transpose_bf16<<<(HID * HID + 255) / 256, 256, 0, stream>>>(W2, W2t, HID);

  // 4) T1t[h][j] = bf16(d_j * (X@W1)[j][h]) : [512 x 8192]
  gemm_bt<0><<<dim3(NN / 64, HID / 128), 256, 0, stream>>>(
      W1t, P0, P1, ddeg, nullptr, HID, NN, IN);
  // 5) parts[z] = Abf * T1t^T (split-K), then out1 = relu(d*sum + b1) -> P0
  gemm_bigRB<<<2 * (NN / 256) * KSPLIT, 512, 0, stream>>>(
      Abf, P1, parts, NN, HID, NN, NN / KSPLIT);
  k_reduce<1><<<(int)((size_t)NN * HID / 8 / 256), 256, 0, stream>>>(
      parts, ddeg, b1, P0, NN, HID);
  // 6) T2t[h][j] = bf16(d_j * (out1@W2)[j][h]) : [512 x 8192]
  gemm_bt<0><<<dim3(NN / 64, HID / 128), 256, 0, stream>>>(
      W2t, P0, P1, ddeg, nullptr, HID, NN, HID);
  // 7) parts[z] = Abf * T2t^T, then out = d*sum + b2 (fp32) -> d_out
  gemm_bigRB<<<2 * (NN / 256) * KSPLIT, 512, 0, stream>>>(
      Abf, P1, parts, NN, HID, NN, NN / KSPLIT);
  k_reduce<2><<<(int)((size_t)NN * HID / 8 / 256), 256, 0, stream>>>(
      parts, ddeg, b2, out, NN, HID);
}

// Round 15
// 259.131 us; speedup vs baseline: 1.3919x; 1.3919x over previous
//
#include <hip/hip_runtime.h>
#include <stdint.h>

// ---------------------------------------------------------------------------
// GCN forward on MI355X (best measured config, r9 = 259.96 us):
//   d = rsqrt(A.sum(1));  out = dA d relu(dA d (X W1) + b1) W2 + b2 (fused)
// Big A_bf GEMMs: 256x256 tile, BK=32, 8 waves, split-K=4, TRIPLE-buffered
// LDS, ONE barrier + ONE counted vmcnt(4) per K-tile (free-run interleave),
// XOR LDS swizzle, XCD-aware placement.
// ---------------------------------------------------------------------------

typedef __attribute__((ext_vector_type(8))) __bf16 bf16x8;
typedef __attribute__((ext_vector_type(4))) float f32x4;
typedef __attribute__((ext_vector_type(8))) unsigned short u16x8;

__device__ __forceinline__ unsigned short f2bf(float f) {
  union { float f; uint32_t u; } v; v.f = f;
  uint32_t u = v.u;
  return (unsigned short)((u + 0x7fffu + ((u >> 16) & 1u)) >> 16);  // RNE
}

__device__ __forceinline__ float bf2f(unsigned short u) {
  union { uint32_t u; float f; } v; v.u = ((uint32_t)u) << 16; return v.f;
}

__device__ __forceinline__ void async_cp16(const void* g, void* lds) {
  auto gp = (const __attribute__((address_space(1))) uint32_t*)g;
  auto lp = (__attribute__((address_space(3))) uint32_t*)lds;
  __builtin_amdgcn_global_load_lds(gp, lp, 16, 0, 0);
}

// --- kernel 1: per-row sum of fp32 A + fp32->bf16 conversion ----------------
__global__ __launch_bounds__(256) void k_rowsum_convert(
    const float* __restrict__ A, unsigned short* __restrict__ Abf,
    float* __restrict__ dvec, int ncols) {
  const int row = blockIdx.x;
  const float* arow = A + (size_t)row * ncols;
  unsigned short* orow = Abf + (size_t)row * ncols;
  float s = 0.f;
  for (int c = threadIdx.x * 4; c < ncols; c += 256 * 4) {
    float4 v = *(const float4*)(arow + c);
    s += (v.x + v.y) + (v.z + v.w);
    ushort4 o;
    o.x = f2bf(v.x); o.y = f2bf(v.y); o.z = f2bf(v.z); o.w = f2bf(v.w);
    *(ushort4*)(orow + c) = o;
  }
  #pragma unroll
  for (int off = 32; off > 0; off >>= 1) s += __shfl_down(s, off);
  __shared__ float red[4];
  if ((threadIdx.x & 63) == 0) red[threadIdx.x >> 6] = s;
  __syncthreads();
  if (threadIdx.x == 0) {
    float t = (red[0] + red[1]) + (red[2] + red[3]);
    dvec[row] = 1.0f / sqrtf(t);
  }
}

// --- kernel 2: elementwise fp32 -> bf16 -------------------------------------
__global__ __launch_bounds__(256) void k_f32_to_bf16(
    const float* __restrict__ in, unsigned short* __restrict__ out, int n4) {
  int i = blockIdx.x * 256 + threadIdx.x;
  if (i < n4) {
    float4 v = ((const float4*)in)[i];
    ushort4 o;
    o.x = f2bf(v.x); o.y = f2bf(v.y); o.z = f2bf(v.z); o.w = f2bf(v.w);
    ((ushort4*)out)[i] = o;
  }
}

// --- kernel 3: transpose + convert 512x512 weight: out[n][k] = in[k][n] -----
__global__ __launch_bounds__(256) void k_transpose_bf16(
    const float* __restrict__ in, unsigned short* __restrict__ out, int dim) {
  int o = blockIdx.x * 256 + threadIdx.x;
  if (o < dim * dim) {
    int k = o % dim;
    int n = o / dim;
    out[o] = f2bf(in[k * dim + n]);
  }
}

// --- small GEMM (proven): C[M,N] = bf16(dvec[col] * Aop[M,K] * Bt[N,K]^T) ---
template <int MODE>
__global__ __launch_bounds__(256, 2) void gemm_bt(
    const unsigned short* __restrict__ Aop,
    const unsigned short* __restrict__ Bt,
    void* __restrict__ Cout,
    const float* __restrict__ dvec,
    const float* __restrict__ bias,
    int M, int N, int K) {
  constexpr int BM = 128, BN = 64, BK = 32;
  __shared__ unsigned short As[BM * BK];
  __shared__ unsigned short Bs[BN * BK];

  const int tid = threadIdx.x;
  const int w = tid >> 6;
  const int l = tid & 63;
  const int rowBase = blockIdx.y * BM;
  const int colBase = blockIdx.x * BN;
  const int waveM = w >> 1;
  const int waveN = w & 1;

  f32x4 acc[4][2];
  const f32x4 fz = {0.f, 0.f, 0.f, 0.f};
  #pragma unroll
  for (int m = 0; m < 4; ++m)
    #pragma unroll
    for (int n = 0; n < 2; ++n) acc[m][n] = fz;

  const int chunkRow = l >> 2;
  const int kOff = (l & 3) * 8;
  const unsigned short* gA0 = Aop + (size_t)(rowBase + w * 16 + chunkRow) * K + kOff;
  const unsigned short* gA1 = gA0 + (size_t)64 * K;
  const unsigned short* gB0 = Bt + (size_t)(colBase + w * 16 + chunkRow) * K + kOff;
  unsigned short* lA0 = As + w * 512;
  unsigned short* lA1 = As + (w + 4) * 512;
  unsigned short* lB0 = Bs + w * 512;

  const int kfrag = (l >> 4) * 8;
  const int lrow = l & 15;

  for (int k0 = 0; k0 < K; k0 += BK) {
    async_cp16(gA0 + k0, lA0);
    async_cp16(gA1 + k0, lA1);
    async_cp16(gB0 + k0, lB0);
    __syncthreads();

    bf16x8 af[4], bfr[2];
    #pragma unroll
    for (int m = 0; m < 4; ++m)
      af[m] = *(const bf16x8*)(As + (waveM * 64 + m * 16 + lrow) * BK + kfrag);
    #pragma unroll
    for (int n = 0; n < 2; ++n)
      bfr[n] = *(const bf16x8*)(Bs + (waveN * 32 + n * 16 + lrow) * BK + kfrag);

    #pragma unroll
    for (int m = 0; m < 4; ++m)
      #pragma unroll
      for (int n = 0; n < 2; ++n)
        acc[m][n] = __builtin_amdgcn_mfma_f32_16x16x32_bf16(af[m], bfr[n],
                                                            acc[m][n], 0, 0, 0);
    __syncthreads();
  }

  const int erow0 = rowBase + waveM * 64 + (l >> 4) * 4;
  const int ecol0 = colBase + waveN * 32 + (l & 15);
  #pragma unroll
  for (int m = 0; m < 4; ++m) {
    #pragma unroll
    for (int n = 0; n < 2; ++n) {
      #pragma unroll
      for (int j = 0; j < 4; ++j) {
        const int rowg = erow0 + m * 16 + j;
        const int colg = ecol0 + n * 16;
        float v = acc[m][n][j];
        if (MODE == 0) {
          v *= dvec[colg];
          ((unsigned short*)Cout)[(size_t)rowg * N + colg] = f2bf(v);
        }
      }
    }
  }
}

// --- big GEMM: Pout[z][M][N] = Aop[M,Kslab] * Bt[N,Kslab]^T (bf16 partial) --
// 256x256 tile, BK=32, 8 waves, TRIPLE-buffered LDS, ONE barrier + ONE
// counted vmcnt(4) per K-tile; reads/stages/MFMAs free-run within the tile.
// Safety ledger: stage(t+2)->buf[(t+2)%3]; at top of tile t, FIFO holds
// pieces(t) [staged t-2] + pieces(t+1) [staged t-1]; vmcnt(4) retires all
// but the newest 4 = pieces(t) complete; barrier publishes them. A wave
// reaching barrier t+1 has issued its tile-t MFMAs, whose lgkm scoreboard
// forced its tile-t ds_reads complete -> buf[t%3] free for stage at t+1.
// Linear grid of 256 blocks; requires M=8192, N=512, KSPLIT=4.
// XCD decode: id = q + 8*s -> z=q>>1, y=(q&1)*16+(s>>1), x=s&1.
__global__ __launch_bounds__(512, 1) void gemm_big3f(
    const unsigned short* __restrict__ Aop,
    const unsigned short* __restrict__ Bt,
    unsigned short* __restrict__ Pout,
    int M, int N, int K, int kLen) {
  constexpr int BK = 32;
  __shared__ char lds[3 * 32768];  // 3 bufs x (A 16KB | B 16KB)

  const int tid = threadIdx.x;
  const int w = tid >> 6;       // 0..7
  const int l = tid & 63;

  // XCD-aware block decode (bijective over 256 blocks = 2 x * 32 y * 4 z)
  const int id = blockIdx.x;
  const int q = id & 7, s = id >> 3;
  const int bx = s & 1;
  const int by = ((q & 1) << 4) | (s >> 1);
  const int bz = q >> 1;

  const int rowBase = by * 256;
  const int colBase = bx * 256;
  const int kBase = bz * kLen;
  const int waveM = w >> 2;     // 0..1 -> 128-row slab
  const int waveN = w & 3;      // 0..3 -> 64-col slab

  f32x4 acc[8][4];
  const f32x4 fz = {0.f, 0.f, 0.f, 0.f};
  #pragma unroll
  for (int m = 0; m < 8; ++m)
    #pragma unroll
    for (int n = 0; n < 4; ++n) acc[m][n] = fz;

  // ---- staging: wave w owns rows [w*32, w*32+32) of the 256-row tile.
  // Each global_load_lds covers 16 rows: lane l -> row R0+(l>>2), slot l&3.
  // Pre-swizzled source slot = (l&3) ^ ((l>>3)&3)  [= slot ^ ((row>>1)&3)].
  const int srcElem = ((l & 3) ^ ((l >> 3) & 3)) * 8;
  const unsigned short* aSrc =
      Aop + (size_t)(rowBase + w * 32 + (l >> 2)) * K + kBase + srcElem;
  const unsigned short* bSrc =
      Bt + (size_t)(colBase + w * 32 + (l >> 2)) * K + kBase + srcElem;
  const int dstTh = w * 2048 + l * 16;  // linear per-wave LDS dest

#define STAGE_A(tt, bb)                                                   \
  {                                                                       \
    const size_t o = (size_t)(tt) * BK;                                   \
    async_cp16(aSrc + o, lds + (bb) + dstTh);                             \
    async_cp16(aSrc + (size_t)16 * K + o, lds + (bb) + dstTh + 1024);     \
  }
#define STAGE_B(tt, bb)                                                   \
  {                                                                       \
    const size_t o = (size_t)(tt) * BK;                                   \
    async_cp16(bSrc + o, lds + (bb) + 16384 + dstTh);                     \
    async_cp16(bSrc + (size_t)16 * K + o, lds + (bb) + 16384 + dstTh + 1024); \
  }

  const int nt = kLen / BK;  // 64
  // prologue: tiles 0,1 into bufs 0,1 (4 loads each, FIFO: A0,B0,A1,B1)
  STAGE_A(0, 0); STAGE_B(0, 0);
  STAGE_A(1, 32768); STAGE_B(1, 32768);

  const int lrow = l & 15;
  const int kq = l >> 4;               // 16B k-slot
  const int xr = (lrow >> 1) & 3;      // (row>>1)&3 for this lane's rows
  const int slotByte = ((kq ^ xr) << 4);
  const int aRow0 = (waveM * 128 + lrow) * 64;
  const int bRow0 = 16384 + (waveN * 64 + lrow) * 64;

  int cur = 0, nxt = 32768, fut = 65536;
  for (int t = 0; t < nt; ++t) {
    // tile t's 4 loads retired; tile t+1's 4 may remain in flight
    if (t == nt - 1) {
      asm volatile("s_waitcnt vmcnt(0)" ::: "memory");
    } else {
      asm volatile("s_waitcnt vmcnt(4)" ::: "memory");
    }
    __builtin_amdgcn_s_barrier();

    // free-run region: reads + stage issues + MFMAs, no internal barriers.
    bf16x8 af[4], bfr[4], af2[4];
    #pragma unroll
    for (int i = 0; i < 4; ++i)
      af[i] = *(const bf16x8*)(lds + cur + aRow0 + i * 16 * 64 + slotByte);
    #pragma unroll
    for (int n = 0; n < 4; ++n)
      bfr[n] = *(const bf16x8*)(lds + cur + bRow0 + n * 16 * 64 + slotByte);
    if (t + 2 < nt) STAGE_A(t + 2, fut);

    #pragma unroll
    for (int i = 0; i < 4; ++i)
      #pragma unroll
      for (int n = 0; n < 4; ++n)
        acc[i][n] = __builtin_amdgcn_mfma_f32_16x16x32_bf16(
            af[i], bfr[n], acc[i][n], 0, 0, 0);

    #pragma unroll
    for (int i = 0; i < 4; ++i)
      af2[i] = *(const bf16x8*)(lds + cur + aRow0 + (64 + i * 16) * 64 + slotByte);
    if (t + 2 < nt) STAGE_B(t + 2, fut);

    #pragma unroll
    for (int i = 0; i < 4; ++i)
      #pragma unroll
      for (int n = 0; n < 4; ++n)
        acc[4 + i][n] = __builtin_amdgcn_mfma_f32_16x16x32_bf16(
            af2[i], bfr[n], acc[4 + i][n], 0, 0, 0);

    const int tmp = cur; cur = nxt; nxt = fut; fut = tmp;
  }
#undef STAGE_A
#undef STAGE_B

  // epilogue: bf16 partial write. C/D layout: col = lane&15, row = (l>>4)*4+j
  unsigned short* pz = Pout + (size_t)bz * M * N;
  const int erow0 = rowBase + waveM * 128 + (l >> 4) * 4;
  const int ecol0 = colBase + waveN * 64 + (l & 15);
  #pragma unroll
  for (int m = 0; m < 8; ++m) {
    #pragma unroll
    for (int n = 0; n < 4; ++n) {
      #pragma unroll
      for (int j = 0; j < 4; ++j) {
        pz[(size_t)(erow0 + m * 16 + j) * N + ecol0 + n * 16] =
            f2bf(acc[m][n][j]);
      }
    }
  }
}

// --- reduce over 4 bf16 partials + epilogue ---------------------------------
// MODE 1: out bf16 = relu(d_row * sum + bias[col])
// MODE 2: out fp32 = d_row * sum + bias[col]
template <int MODE>
__global__ __launch_bounds__(256) void k_reduce(
    const unsigned short* __restrict__ parts,
    const float* __restrict__ dvec,
    const float* __restrict__ bias,
    void* __restrict__ outp, int M, int N) {
  const size_t MN = (size_t)M * N;
  const size_t idx = ((size_t)blockIdx.x * 256 + threadIdx.x) * 8;
  if (idx >= MN) return;
  const int row = (int)(idx / N);
  const int col = (int)(idx % N);
  const float di = dvec[row];
  float s[8] = {0, 0, 0, 0, 0, 0, 0, 0};
  #pragma unroll
  for (int z = 0; z < 4; ++z) {
    u16x8 v = *(const u16x8*)(parts + z * MN + idx);
    #pragma unroll
    for (int e = 0; e < 8; ++e) s[e] += bf2f(v[e]);
  }
  if (MODE == 1) {
    ushort4 o0, o1;
    unsigned short tmp[8];
    #pragma unroll
    for (int e = 0; e < 8; ++e) {
      float v = di * s[e] + bias[col + e];
      v = v > 0.f ? v : 0.f;
      tmp[e] = f2bf(v);
    }
    o0.x = tmp[0]; o0.y = tmp[1]; o0.z = tmp[2]; o0.w = tmp[3];
    o1.x = tmp[4]; o1.y = tmp[5]; o1.z = tmp[6]; o1.w = tmp[7];
    *(ushort4*)((unsigned short*)outp + idx) = o0;
    *(ushort4*)((unsigned short*)outp + idx + 4) = o1;
  } else {
    float4 o0, o1;
    o0.x = di * s[0] + bias[col + 0];
    o0.y = di * s[1] + bias[col + 1];
    o0.z = di * s[2] + bias[col + 2];
    o0.w = di * s[3] + bias[col + 3];
    o1.x = di * s[4] + bias[col + 4];
    o1.y = di * s[5] + bias[col + 5];
    o1.z = di * s[6] + bias[col + 6];
    o1.w = di * s[7] + bias[col + 7];
    *(float4*)((float*)outp + idx) = o0;
    *(float4*)((float*)outp + idx + 4) = o1;
  }
}

extern "C" void kernel_launch(void* const* d_in, const int* in_sizes, int n_in,
                              void* d_out, int out_size, void* d_ws, size_t ws_size,
                              hipStream_t stream) {
  const float* X  = (const float*)d_in[0];   // [8192, 512]
  const float* A  = (const float*)d_in[1];   // [8192, 8192]
  const float* W1 = (const float*)d_in[2];   // [512, 512]
  const float* b1 = (const float*)d_in[3];   // [512]
  const float* W2 = (const float*)d_in[4];   // [512, 512]
  const float* b2 = (const float*)d_in[5];   // [512]
  float* out = (float*)d_out;                // [8192, 512] fp32

  constexpr int NN = 8192, IN = 512, HID = 512;
  constexpr int KSPLIT = 4;

  // workspace (~177 MiB): d | A_bf | W1t | W2t | P0 | P1 | parts
  char* ws = (char*)d_ws;
  float* ddeg = (float*)ws;                                        // 32KB
  unsigned short* Abf = (unsigned short*)(ws + (32 << 10));        // 128MiB
  unsigned short* W1t = Abf + (size_t)NN * NN;                     // 512KiB
  unsigned short* W2t = W1t + IN * HID;                            // 512KiB
  unsigned short* P0  = W2t + HID * HID;                           // 8MiB
  unsigned short* P1  = P0 + (size_t)NN * HID;                     // 8MiB
  unsigned short* parts = P1 + (size_t)NN * HID;                   // 32MiB

  // 1) degrees + A -> bf16
  k_rowsum_convert<<<NN, 256, 0, stream>>>(A, Abf, ddeg, NN);
  // 2) X -> bf16 (into P0)
  k_f32_to_bf16<<<(NN * IN / 4 + 255) / 256, 256, 0, stream>>>(X, P0, NN * IN / 4);
  // 3) weights transposed+bf16
  k_transpose_bf16<<<(IN * HID + 255) / 256, 256, 0, stream>>>(W1, W1t, IN);
  k_transpose_bf16<<<(HID * HID + 255) / 256, 256, 0, stream>>>(W2, W2t, HID);

  // 4) T1t[h][j] = bf16(d_j * (X@W1)[j][h]) : [512 x 8192]
  gemm_bt<0><<<dim3(NN / 64, HID / 128), 256, 0, stream>>>(
      W1t, P0, P1, ddeg, nullptr, HID, NN, IN);
  // 5) parts[z] = Abf * T1t^T (split-K), then out1 = relu(d*sum + b1) -> P0
  gemm_big3f<<<2 * (NN / 256) * KSPLIT, 512, 0, stream>>>(
      Abf, P1, parts, NN, HID, NN, NN / KSPLIT);
  k_reduce<1><<<(int)((size_t)NN * HID / 8 / 256), 256, 0, stream>>>(
      parts, ddeg, b1, P0, NN, HID);
  // 6) T2t[h][j] = bf16(d_j * (out1@W2)[j][h]) : [512 x 8192]
  gemm_bt<0><<<dim3(NN / 64, HID / 128), 256, 0, stream>>>(
      W2t, P0, P1, ddeg, nullptr, HID, NN, HID);
  // 7) parts[z] = Abf * T2t^T, then out = d*sum + b2 (fp32) -> d_out
  gemm_big3f<<<2 * (NN / 256) * KSPLIT, 512, 0, stream>>>(
      Abf, P1, parts, NN, HID, NN, NN / KSPLIT);
  k_reduce<2><<<(int)((size_t)NN * HID / 8 / 256), 256, 0, stream>>>(
      parts, ddeg, b2, out, NN, HID);
}